// Round 16
// baseline (98.778 us; speedup 1.0000x reference)
//
#include <hip/hip_runtime.h>
#include <hip/hip_bf16.h>

// FourierKANLayer: y[n,o] = sum_{i,g} cos(x[n,i]*(g+1))*C[0,o,i,g]
//                         + sin(x[n,i]*(g+1))*C[1,o,i,g] + bias[o]
// N=8192, I=512, O=512, G=8  ->  GEMM [N x K]*[K x O], K = I*16 = 8192
// Round 16: m201-style 8-phase schedule. 256x256 tile, 8 waves (2Mx4N, wave
// tile 128x64), BK=64 K-tiles, 2 LDS slots, 4 phases/K-tile:
//   {ds_read A-quad [+B at q0] | stage-slice (q0: 4 B-gloads; q1/q2: sincos+
//    A-write; q3: x-prefetch + counted vmcnt(1)) -> barrier -> lgkmcnt(0)+
//    sched_barrier -> setprio(1) -> 8 MFMA -> setprio(0) -> barrier}
// Counted vmcnt never 0 in steady state (T3+T4); T5 setprio pays only in
// this phase-split regime (catalog regime-gate).

typedef __attribute__((ext_vector_type(8)))  short s16x8;
typedef __attribute__((ext_vector_type(4)))  int   i32x4;
typedef __attribute__((ext_vector_type(4)))  float f32x4;
typedef __attribute__((ext_vector_type(16))) float f32x16;

#define NROWS 8192
#define IDIM  512
#define ODIM  512
#define KDIM  8192   // IDIM*16

static __device__ __forceinline__ short f2bf(float f) {
    union { float f; unsigned u; } v; v.f = f;
    unsigned r = v.u + 0x7fffu + ((v.u >> 16) & 1u);  // RNE
    return (short)(r >> 16);
}

static __device__ __forceinline__ float bf2f(short h) {
    union { unsigned u; float f; } v;
    v.u = ((unsigned)(unsigned short)h) << 16;
    return v.f;
}

static __device__ __forceinline__ int pkbf(float c, float s) {
    union { __hip_bfloat162 h; int i; } u;
    u.h = __float22bfloat162_rn(make_float2(c, s));   // low = cos, high = sin
    return u.i;
}

// ---- prep: coeffs [2][O][I][G] f32  ->  Wb[O][K] bf16, k = i*16 + 2g + t ----
__global__ __launch_bounds__(256) void fkan_prep(const float* __restrict__ cf,
                                                 short* __restrict__ Wb) {
    const int o = blockIdx.x;
    const int tid = threadIdx.x;
#pragma unroll
    for (int rep = 0; rep < 2; ++rep) {
        const int i = tid + rep * 256;
        const float* c0 = cf + (o * 512 + i) * 8;            // t=0
        const float* c1 = cf + ((512 + o) * 512 + i) * 8;    // t=1
        float4 a0 = *(const float4*)c0;
        float4 a1 = *(const float4*)(c0 + 4);
        float4 b0 = *(const float4*)c1;
        float4 b1 = *(const float4*)(c1 + 4);
        s16x8 lo, hi;
        lo[0] = f2bf(a0.x); lo[1] = f2bf(b0.x);
        lo[2] = f2bf(a0.y); lo[3] = f2bf(b0.y);
        lo[4] = f2bf(a0.z); lo[5] = f2bf(b0.z);
        lo[6] = f2bf(a0.w); lo[7] = f2bf(b0.w);
        hi[0] = f2bf(a1.x); hi[1] = f2bf(b1.x);
        hi[2] = f2bf(a1.y); hi[3] = f2bf(b1.y);
        hi[4] = f2bf(a1.z); hi[5] = f2bf(b1.z);
        hi[6] = f2bf(a1.w); hi[7] = f2bf(b1.w);
        *(s16x8*)(Wb + o * KDIM + i * 16)     = lo;
        *(s16x8*)(Wb + o * KDIM + i * 16 + 8) = hi;
    }
}

// ---- main GEMM: BM=256, BN=256, BK=64, 512 threads (8 waves, 2x4) ----
// grid 256 (32 bm x 2 bn x 4 kc), 1 block/CU. 8-phase schedule, 32x32x16.
__global__ __launch_bounds__(512, 2) void fkan_gemm16(const float* __restrict__ x,
                                                      const short* __restrict__ Wb,
                                                      short* __restrict__ P) {
    // A: [256 rows][72 shorts] (144B stride = 64 data + 8 pad, bank-rotated).
    // B: [256 rows][64 shorts]; chunk cb stored at slot cb ^ (row&7) (rule 21,
    //    R3-proven geometry).
    __shared__ short As[2][256 * 72];   // 2 x 36 KB
    __shared__ short Bs[2][256 * 64];   // 2 x 32 KB

    const int bid = blockIdx.x;
    const int xcd = bid & 7;
    const int bn = xcd & 1, kc = xcd >> 1;          // 8 (bn,kc) combos -> 8 XCDs
    const int bm = bid >> 3;                        // [0,32)
    const int n0 = bm * 256, o0 = bn * 256, i0 = kc * 128;
    const int kbase = i0 * 16;
    const int NT = 32;                              // K-tiles of 64 (128 i / 4)

    const int tid = threadIdx.x;
    const int wid = tid >> 6, lane = tid & 63;
    const int l32 = lane & 31, hi32 = lane >> 5;
    const int wr = wid >> 2, wc = wid & 3;          // 2(M) x 4(N) wave grid

    f32x16 acc[4][2];                               // [mt][nt], 128 f32
#pragma unroll
    for (int a = 0; a < 4; ++a)
#pragma unroll
        for (int b = 0; b < 2; ++b)
#pragma unroll
            for (int e = 0; e < 16; ++e) acc[a][b][e] = 0.f;

    // A staging: thread -> row tid>>1, i-half h=tid&1 (i_local {2h,2h+1} per sincos pair)
    const int arow_s = tid >> 1, hsel = tid & 1;
    const float* xptr = x + (size_t)(n0 + arow_s) * 512 + i0 + 2 * hsel;
    float2 xv;                                       // x for the tile being staged

    // stage helpers ------------------------------------------------------
    auto stageB = [&](int t, short* Bw) {             // 4 gload_lds, rule-21 src
#pragma unroll
        for (int w = 0; w < 4; ++w) {
            const int ch = w * 512 + tid;             // physical chunk
            const int l = ch >> 3, sl = ch & 7;
            const int cb = sl ^ (l & 7);
            const short* src = Wb + (size_t)(o0 + l) * KDIM + kbase + t * 64 + cb * 8;
            short* ldst = Bw + w * 4096 + wid * 512;  // wave-uniform base
            __builtin_amdgcn_global_load_lds(
                (const __attribute__((address_space(1))) void*)src,
                (__attribute__((address_space(3))) void*)ldst, 16, 0, 0);
        }
    };
    auto stageA1 = [&](short* Aw, float xx, int j) {  // one sincos -> 2 chunks
        float s1, c1;
        __sincosf(xx, &s1, &c1);
        float c = c1, s = s1;
        i32x4 lo, hi;
#pragma unroll
        for (int g = 0; g < 8; ++g) {
            const int p = pkbf(c, s);
            if (g < 4) lo[g] = p; else hi[g - 4] = p;
            const float t1 = s * s1, t2 = c * s1;
            const float cn = __builtin_fmaf(c, c1, -t1);
            s = __builtin_fmaf(s, c1, t2);
            c = cn;
        }
        const int il = 2 * hsel + j;                  // i_local 0..3
        *(i32x4*)&Aw[arow_s * 72 + il * 16]     = lo;
        *(i32x4*)&Aw[arow_s * 72 + il * 16 + 8] = hi;
    };

    // one K-tile = 4 phases --------------------------------------------
    auto group = [&](int t, const short* Ar, const short* Br,
                     short* Aw, short* Bw, bool stg, bool ldx) {
        s16x8 bfr[2][4];
#pragma unroll
        for (int q = 0; q < 4; ++q) {
            // ---- ds reads for this phase
            if (q == 0) {
#pragma unroll
                for (int nt = 0; nt < 2; ++nt)
#pragma unroll
                    for (int kk = 0; kk < 4; ++kk) {
                        const int row = wc * 64 + nt * 32 + l32;
                        const int cb = kk * 2 + hi32;
                        bfr[nt][kk] = *(const s16x8*)&Br[row * 64 + (cb ^ (row & 7)) * 8];
                    }
            }
            s16x8 af[4];
            {
                const int row = wr * 128 + q * 32 + l32;
#pragma unroll
                for (int kk = 0; kk < 4; ++kk)
                    af[kk] = *(const s16x8*)&Ar[row * 72 + (kk * 2 + hi32) * 8];
            }
            // ---- staging slice
            if (q == 0 && stg) stageB(t + 1, Bw);
            if (q == 1 && stg) stageA1(Aw, xv.x, 0);
            if (q == 2 && stg) stageA1(Aw, xv.y, 1);
            if (q == 3) {
                if (ldx) xv = *(const float2*)(xptr + (t + 2) * 4);
                if (ldx)      asm volatile("s_waitcnt vmcnt(1)" ::: "memory");
                else if (stg) asm volatile("s_waitcnt vmcnt(0)" ::: "memory");
                __builtin_amdgcn_sched_barrier(0);
            }
            __builtin_amdgcn_s_barrier();
            asm volatile("s_waitcnt lgkmcnt(0)" ::: "memory");
            __builtin_amdgcn_sched_barrier(0);
            __builtin_amdgcn_s_setprio(1);
#pragma unroll
            for (int kk = 0; kk < 4; ++kk)
#pragma unroll
                for (int nt = 0; nt < 2; ++nt)
                    acc[q][nt] = __builtin_amdgcn_mfma_f32_32x32x16_bf16(
                        af[kk], bfr[nt][kk], acc[q][nt], 0, 0, 0);
            __builtin_amdgcn_s_setprio(0);
            __builtin_amdgcn_s_barrier();
        }
    };

    // ---- prologue: stage tile 0, prefetch x(tile 1)
    {
        float2 x0 = *(const float2*)(xptr);           // tile 0 (waited at use)
        stageB(0, Bs[0]);
        stageA1(As[0], x0.x, 0);
        stageA1(As[0], x0.y, 1);
        xv = *(const float2*)(xptr + 4);              // tile 1
        asm volatile("s_waitcnt vmcnt(1) lgkmcnt(0)" ::: "memory");
        __builtin_amdgcn_sched_barrier(0);
        __builtin_amdgcn_s_barrier();
    }

#pragma unroll 1
    for (int tp = 0; tp < 16; ++tp) {
        const int t0 = tp * 2;
        group(t0,     As[0], Bs[0], As[1], Bs[1], true,          t0 + 2 < NT);
        group(t0 + 1, As[1], Bs[1], As[0], Bs[0], t0 + 2 < NT,   t0 + 3 < NT);
    }

    // ---- epilogue: bf16 partial. 32x32 D layout: col = lane&31,
    //      row = (reg&3) + 8*(reg>>2) + 4*(lane>>5)   [m74/m101]
    unsigned short* dst = (unsigned short*)P + (size_t)kc * (NROWS * ODIM);
#pragma unroll
    for (int mt = 0; mt < 4; ++mt)
#pragma unroll
        for (int nt = 0; nt < 2; ++nt) {
            const f32x16 v = acc[mt][nt];
            const int oc = o0 + wc * 64 + nt * 32 + l32;
            const int rb = n0 + wr * 128 + mt * 32 + 4 * hi32;
#pragma unroll
            for (int reg = 0; reg < 16; ++reg) {
                const int row = rb + (reg & 3) + 8 * (reg >> 2);
                dst[(size_t)row * 512 + oc] = (unsigned short)f2bf(v[reg]);
            }
        }
}

// ---- combine: out = sum_{q<4} f32(Pq) + bias ----
__global__ __launch_bounds__(256) void fkan_combine4(const short* __restrict__ P,
                                                     const float* __restrict__ bias,
                                                     float* __restrict__ out) {
    const int total = NROWS * ODIM;
    const int stride = gridDim.x * 256 * 8;
    for (int e = (blockIdx.x * 256 + threadIdx.x) * 8; e < total; e += stride) {
        s16x8 a = *(const s16x8*)(P + e);
        s16x8 b = *(const s16x8*)(P + total + e);
        s16x8 c = *(const s16x8*)(P + 2 * total + e);
        s16x8 d = *(const s16x8*)(P + 3 * total + e);
        const int col = e & 511;
        float4 c0 = *(const float4*)(bias + col);
        float4 c1 = *(const float4*)(bias + col + 4);
        float4 r0, r1;
        r0.x = (bf2f(a[0]) + bf2f(b[0])) + (bf2f(c[0]) + bf2f(d[0])) + c0.x;
        r0.y = (bf2f(a[1]) + bf2f(b[1])) + (bf2f(c[1]) + bf2f(d[1])) + c0.y;
        r0.z = (bf2f(a[2]) + bf2f(b[2])) + (bf2f(c[2]) + bf2f(d[2])) + c0.z;
        r0.w = (bf2f(a[3]) + bf2f(b[3])) + (bf2f(c[3]) + bf2f(d[3])) + c0.w;
        r1.x = (bf2f(a[4]) + bf2f(b[4])) + (bf2f(c[4]) + bf2f(d[4])) + c1.x;
        r1.y = (bf2f(a[5]) + bf2f(b[5])) + (bf2f(c[5]) + bf2f(d[5])) + c1.y;
        r1.z = (bf2f(a[6]) + bf2f(b[6])) + (bf2f(c[6]) + bf2f(d[6])) + c1.z;
        r1.w = (bf2f(a[7]) + bf2f(b[7])) + (bf2f(c[7]) + bf2f(d[7])) + c1.w;
        *(float4*)(out + e)     = r0;
        *(float4*)(out + e + 4) = r1;
    }
}

// ---- fallback (small ws): KSPLIT=1 structure, grid 256, f32 out + bias ----
__global__ __launch_bounds__(256, 2) void fkan_gemm_fb(const float* __restrict__ x,
                                                       const short* __restrict__ Wb,
                                                       const float* __restrict__ bias,
                                                       float* __restrict__ outp) {
    __shared__ short As[2][128 * 64];
    __shared__ short Bs[2][128 * 64];
    const int bid = blockIdx.x;
    const int xcd = bid & 7, idx = bid >> 3;
    const int bn = xcd & 3, bm = idx + (xcd >> 2) * 32;
    const int n0 = bm * 128, o0 = bn * 128;
    const int tid = threadIdx.x;
    const int wid = tid >> 6, lane = tid & 63;
    const int lrow = lane & 15, lk = lane >> 4;
    const int wr = wid >> 1, wc = wid & 1;
    f32x4 acc[4][4];
#pragma unroll
    for (int a = 0; a < 4; ++a)
#pragma unroll
        for (int b = 0; b < 4; ++b) { f32x4 z = {0,0,0,0}; acc[a][b] = z; }
    const int nl = tid >> 1, isel = tid & 1;
    const float* xrow = x + (n0 + nl) * 512 + isel * 2;
    auto stage = [&](int t, int nb, float2 xvv) {
#pragma unroll
        for (int w = 0; w < 4; ++w) {
            const int chunk = w * 256 + tid;
            const int r = chunk >> 3, pc = chunk & 7;
            const int lc = pc ^ (r & 7);
            const short* src = Wb + (o0 + r) * KDIM + t * 64 + lc * 8;
            short* ldst = &Bs[nb][w * 2048 + wid * 512];
            __builtin_amdgcn_global_load_lds(
                (const __attribute__((address_space(1))) void*)src,
                (__attribute__((address_space(3))) void*)ldst, 16, 0, 0);
        }
#pragma unroll
        for (int ii = 0; ii < 2; ++ii) {
            const float xx = ii ? xvv.y : xvv.x;
            float s1, c1; __sincosf(xx, &s1, &c1);
            float c = c1, s = s1;
            i32x4 lo, hi;
#pragma unroll
            for (int g = 0; g < 8; ++g) {
                const int p = pkbf(c, s);
                if (g < 4) lo[g] = p; else hi[g - 4] = p;
                const float t1 = s * s1, t2 = c * s1;
                const float cn = __builtin_fmaf(c, c1, -t1);
                s = __builtin_fmaf(s, c1, t2); c = cn;
            }
            const int cb0 = (isel * 2 + ii) * 2;
            *(i32x4*)&As[nb][nl * 64 + ((cb0 ^ (nl & 7))) * 8]       = lo;
            *(i32x4*)&As[nb][nl * 64 + (((cb0 + 1) ^ (nl & 7))) * 8] = hi;
        }
    };
    float2 xv = *(const float2*)xrow;
    stage(0, 0, xv);
    xv = *(const float2*)(xrow + 4);
    __syncthreads();
    for (int kt = 0; kt < 128; ++kt) {
        const int cur = kt & 1;
        s16x8 af[2][4], bfr[2][4];
#pragma unroll
        for (int ksub = 0; ksub < 2; ++ksub) {
#pragma unroll
            for (int mf = 0; mf < 4; ++mf) {
                const int row = wr * 64 + mf * 16 + lrow;
                af[ksub][mf] = *(const s16x8*)&As[cur][row * 64 + ((ksub * 4 + lk) ^ (row & 7)) * 8];
            }
#pragma unroll
            for (int nf = 0; nf < 4; ++nf) {
                const int row = wc * 64 + nf * 16 + lrow;
                bfr[ksub][nf] = *(const s16x8*)&Bs[cur][row * 64 + ((ksub * 4 + lk) ^ (row & 7)) * 8];
            }
        }
        if (kt + 1 < 128) {
            stage(kt + 1, cur ^ 1, xv);
            if (kt + 2 < 128) xv = *(const float2*)(xrow + (kt + 2) * 4);
        }
#pragma unroll
        for (int ksub = 0; ksub < 2; ++ksub)
#pragma unroll
            for (int mf = 0; mf < 4; ++mf)
#pragma unroll
                for (int nf = 0; nf < 4; ++nf)
                    acc[mf][nf] = __builtin_amdgcn_mfma_f32_16x16x32_bf16(
                        af[ksub][mf], bfr[ksub][nf], acc[mf][nf], 0, 0, 0);
        __syncthreads();
    }
#pragma unroll
    for (int nf = 0; nf < 4; ++nf) {
        const int oc = o0 + wc * 64 + nf * 16 + lrow;
        const float bv = bias[oc];
#pragma unroll
        for (int mf = 0; mf < 4; ++mf) {
            const f32x4 v = acc[mf][nf];
            const int rbase = n0 + wr * 64 + mf * 16 + lk * 4;
#pragma unroll
            for (int j = 0; j < 4; ++j)
                outp[(size_t)(rbase + j) * 512 + oc] = v[j] + bv;
        }
    }
}

extern "C" void kernel_launch(void* const* d_in, const int* in_sizes, int n_in,
                              void* d_out, int out_size, void* d_ws, size_t ws_size,
                              hipStream_t stream) {
    const float* x    = (const float*)d_in[0];
    const float* cf   = (const float*)d_in[1];
    const float* bias = (const float*)d_in[2];
    float* out = (float*)d_out;

    const size_t partial_bytes = (size_t)4 * NROWS * ODIM * 2;   // 33.6 MB (bf16 x4)
    const size_t wb_bytes = (size_t)ODIM * KDIM * 2;             // 8.4 MB

    if (ws_size >= partial_bytes + wb_bytes) {
        short* P  = (short*)d_ws;
        short* Wb = (short*)((char*)d_ws + partial_bytes);
        fkan_prep<<<512, 256, 0, stream>>>(cf, Wb);
        fkan_gemm16<<<256, 512, 0, stream>>>(x, Wb, P);
        fkan_combine4<<<2048, 256, 0, stream>>>(P, bias, out);
    } else {
        short* Wb = (short*)d_ws;
        fkan_prep<<<512, 256, 0, stream>>>(cf, Wb);
        fkan_gemm_fb<<<256, 256, 0, stream>>>(x, Wb, bias, out);
    }
}

// Round 17
// 84.773 us; speedup vs baseline: 1.1652x; 1.1652x over previous
//
#include <hip/hip_runtime.h>
#include <hip/hip_bf16.h>

// FourierKANLayer: y[n,o] = sum_{i,g} cos(x[n,i]*(g+1))*C[0,o,i,g]
//                         + sin(x[n,i]*(g+1))*C[1,o,i,g] + bias[o]
// N=8192, I=512, O=512, G=8  ->  GEMM [N x K]*[K x O], K = I*16 = 8192
// Round 17: R15 (best: 75.8us gemm = 904 TF) with BK 32->64. Halves barrier
// count (64->32) and doubles MFMA per barrier interval (32/wave = 2048
// issue-cyc/SIMD), amortizing the fixed reads+barrier cost and widening the
// window for the two co-SIMD waves to desync into MFMA||VALU overlap (m114).
// A: [256][72] shorts (144B stride, R16-measured low-conflict). B: [256][64]
// row-XOR (R3-proven). LDS 136KB, 1 block/CU.

typedef __attribute__((ext_vector_type(8)))  short s16x8;
typedef __attribute__((ext_vector_type(4)))  int   i32x4;
typedef __attribute__((ext_vector_type(4)))  float f32x4;
typedef __attribute__((ext_vector_type(16))) float f32x16;

#define NROWS 8192
#define IDIM  512
#define ODIM  512
#define KDIM  8192   // IDIM*16

static __device__ __forceinline__ short f2bf(float f) {
    union { float f; unsigned u; } v; v.f = f;
    unsigned r = v.u + 0x7fffu + ((v.u >> 16) & 1u);  // RNE
    return (short)(r >> 16);
}

static __device__ __forceinline__ float bf2f(short h) {
    union { unsigned u; float f; } v;
    v.u = ((unsigned)(unsigned short)h) << 16;
    return v.f;
}

static __device__ __forceinline__ int pkbf(float c, float s) {
    union { __hip_bfloat162 h; int i; } u;
    u.h = __float22bfloat162_rn(make_float2(c, s));   // low = cos, high = sin
    return u.i;
}

// ---- prep: coeffs [2][O][I][G] f32  ->  Wb[O][K] bf16, k = i*16 + 2g + t ----
__global__ __launch_bounds__(256) void fkan_prep(const float* __restrict__ cf,
                                                 short* __restrict__ Wb) {
    const int o = blockIdx.x;
    const int tid = threadIdx.x;
#pragma unroll
    for (int rep = 0; rep < 2; ++rep) {
        const int i = tid + rep * 256;
        const float* c0 = cf + (o * 512 + i) * 8;            // t=0
        const float* c1 = cf + ((512 + o) * 512 + i) * 8;    // t=1
        float4 a0 = *(const float4*)c0;
        float4 a1 = *(const float4*)(c0 + 4);
        float4 b0 = *(const float4*)c1;
        float4 b1 = *(const float4*)(c1 + 4);
        s16x8 lo, hi;
        lo[0] = f2bf(a0.x); lo[1] = f2bf(b0.x);
        lo[2] = f2bf(a0.y); lo[3] = f2bf(b0.y);
        lo[4] = f2bf(a0.z); lo[5] = f2bf(b0.z);
        lo[6] = f2bf(a0.w); lo[7] = f2bf(b0.w);
        hi[0] = f2bf(a1.x); hi[1] = f2bf(b1.x);
        hi[2] = f2bf(a1.y); hi[3] = f2bf(b1.y);
        hi[4] = f2bf(a1.z); hi[5] = f2bf(b1.z);
        hi[6] = f2bf(a1.w); hi[7] = f2bf(b1.w);
        *(s16x8*)(Wb + o * KDIM + i * 16)     = lo;
        *(s16x8*)(Wb + o * KDIM + i * 16 + 8) = hi;
    }
}

// ---- main GEMM: BM=256, BN=256, BK=64, 512 threads (8 waves, 2x4) ----
// grid 256 (32 bm x 2 bn x 4 kc), 1 block/CU, 2 waves/SIMD. Wave tile 128x64.
__global__ __launch_bounds__(512, 2) void fkan_gemm17(const float* __restrict__ x,
                                                      const short* __restrict__ Wb,
                                                      short* __restrict__ P) {
    // A: [256 rows][72 shorts] (144B stride = 128B data + 16B pad).
    // B: [256 rows][64 shorts]; chunk cb at slot cb ^ (row&7) (rule 21).
    __shared__ short As[2][256 * 72];   // 2 x 36 KB
    __shared__ short Bs[2][256 * 64];   // 2 x 32 KB

    const int bid = blockIdx.x;
    const int xcd = bid & 7;
    const int bn = xcd & 1, kc = xcd >> 1;          // 8 (bn,kc) combos -> 8 XCDs
    const int bm = bid >> 3;                        // [0,32)
    const int n0 = bm * 256, o0 = bn * 256, i0 = kc * 128;
    const int kbase = i0 * 16;
    const int NKT = 32;                             // 128 i / 4 i-per-tile

    const int tid = threadIdx.x;
    const int wid = tid >> 6, lane = tid & 63;
    const int l32 = lane & 31, hi32 = lane >> 5;
    const int wr = wid >> 2, wc = wid & 3;          // 2(M) x 4(N) wave grid

    f32x16 acc[4][2];                               // [mt][nt], 128 f32
#pragma unroll
    for (int a = 0; a < 4; ++a)
#pragma unroll
        for (int b = 0; b < 2; ++b)
#pragma unroll
            for (int e = 0; e < 16; ++e) acc[a][b][e] = 0.f;

    // A staging: thread -> row tid>>1, i-half h=tid&1 -> i_local {2h, 2h+1}
    const int arow_s = tid >> 1, hsel = tid & 1;
    const float* xptr = x + (size_t)(n0 + arow_s) * 512 + i0 + 2 * hsel;

    auto stage = [&](int t, int nb, float2 xv2) {
        // ---- B: 32KB = 2048 x 16B chunks, 4 gload_lds per thread (rule 21)
#pragma unroll
        for (int w = 0; w < 4; ++w) {
            const int ch = w * 512 + tid;           // physical chunk index
            const int l = ch >> 3, sl = ch & 7;
            const int cb = sl ^ (l & 7);            // logical chunk at this slot
            const short* src = Wb + (size_t)(o0 + l) * KDIM + kbase + t * 64 + cb * 8;
            short* ldst = &Bs[nb][w * 4096 + wid * 512];  // wave-uniform base
            __builtin_amdgcn_global_load_lds(
                (const __attribute__((address_space(1))) void*)src,
                (__attribute__((address_space(3))) void*)ldst, 16, 0, 0);
        }
        // ---- A: 2 sincos (i_local 2h, 2h+1) -> 4 x 16B chunks
        short* Ab = As[nb];
#pragma unroll
        for (int j = 0; j < 2; ++j) {
            const float xx = j ? xv2.y : xv2.x;
            float s1, c1;
            __sincosf(xx, &s1, &c1);
            float c = c1, s = s1;
            i32x4 lo, hi;
#pragma unroll
            for (int g = 0; g < 8; ++g) {
                const int p = pkbf(c, s);
                if (g < 4) lo[g] = p; else hi[g - 4] = p;
                const float t1 = s * s1, t2 = c * s1;
                const float cn = __builtin_fmaf(c, c1, -t1);
                s = __builtin_fmaf(s, c1, t2);
                c = cn;
            }
            const int il = 2 * hsel + j;            // i_local 0..3
            *(i32x4*)&Ab[arow_s * 72 + il * 16]     = lo;
            *(i32x4*)&Ab[arow_s * 72 + il * 16 + 8] = hi;
        }
    };

    float2 xv = *(const float2*)xptr;               // tile 0
    stage(0, 0, xv);
    xv = *(const float2*)(xptr + 4);                // tile 1
    __syncthreads();

    for (int kt = 0; kt < NKT; ++kt) {
        const int cur = kt & 1;

        // ---- fragment reads: A row = wr*128+mt*32+l32, chunk kk*2+hi32
        s16x8 af[4][4], bfr[2][4];      // [mt][kk], [nt][kk]
#pragma unroll
        for (int mt = 0; mt < 4; ++mt)
#pragma unroll
            for (int kk = 0; kk < 4; ++kk) {
                const int row = wr * 128 + mt * 32 + l32;
                af[mt][kk] = *(const s16x8*)&As[cur][row * 72 + (kk * 2 + hi32) * 8];
            }
#pragma unroll
        for (int nt = 0; nt < 2; ++nt)
#pragma unroll
            for (int kk = 0; kk < 4; ++kk) {
                const int row = wc * 64 + nt * 32 + l32;
                const int cb = kk * 2 + hi32;
                bfr[nt][kk] = *(const s16x8*)&Bs[cur][row * 64 + (cb ^ (row & 7)) * 8];
            }

        // ---- stage next tile into the other buffer (overlaps with MFMA)
        if (kt + 1 < NKT) {
            stage(kt + 1, cur ^ 1, xv);
            if (kt + 2 < NKT) xv = *(const float2*)(xptr + (kt + 2) * 4);
        }

        // ---- MFMA: 32 x 32x32x16 per wave per K-tile (2048 issue-cyc/SIMD)
#pragma unroll
        for (int kk = 0; kk < 4; ++kk)
#pragma unroll
            for (int mt = 0; mt < 4; ++mt)
#pragma unroll
                for (int nt = 0; nt < 2; ++nt)
                    acc[mt][nt] = __builtin_amdgcn_mfma_f32_32x32x16_bf16(
                        af[mt][kk], bfr[nt][kk], acc[mt][nt], 0, 0, 0);

        __syncthreads();
    }

    // ---- epilogue: bf16 partial. 32x32 D layout: col = lane&31,
    //      row = (reg&3) + 8*(reg>>2) + 4*(lane>>5)   [m74/m101]
    unsigned short* dst = (unsigned short*)P + (size_t)kc * (NROWS * ODIM);
#pragma unroll
    for (int mt = 0; mt < 4; ++mt)
#pragma unroll
        for (int nt = 0; nt < 2; ++nt) {
            const f32x16 v = acc[mt][nt];
            const int oc = o0 + wc * 64 + nt * 32 + l32;
            const int rb = n0 + wr * 128 + mt * 32 + 4 * hi32;
#pragma unroll
            for (int reg = 0; reg < 16; ++reg) {
                const int row = rb + (reg & 3) + 8 * (reg >> 2);
                dst[(size_t)row * 512 + oc] = (unsigned short)f2bf(v[reg]);
            }
        }
}

// ---- combine: out = sum_{q<4} f32(Pq) + bias ----
__global__ __launch_bounds__(256) void fkan_combine4(const short* __restrict__ P,
                                                     const float* __restrict__ bias,
                                                     float* __restrict__ out) {
    const int total = NROWS * ODIM;
    const int stride = gridDim.x * 256 * 8;
    for (int e = (blockIdx.x * 256 + threadIdx.x) * 8; e < total; e += stride) {
        s16x8 a = *(const s16x8*)(P + e);
        s16x8 b = *(const s16x8*)(P + total + e);
        s16x8 c = *(const s16x8*)(P + 2 * total + e);
        s16x8 d = *(const s16x8*)(P + 3 * total + e);
        const int col = e & 511;
        float4 c0 = *(const float4*)(bias + col);
        float4 c1 = *(const float4*)(bias + col + 4);
        float4 r0, r1;
        r0.x = (bf2f(a[0]) + bf2f(b[0])) + (bf2f(c[0]) + bf2f(d[0])) + c0.x;
        r0.y = (bf2f(a[1]) + bf2f(b[1])) + (bf2f(c[1]) + bf2f(d[1])) + c0.y;
        r0.z = (bf2f(a[2]) + bf2f(b[2])) + (bf2f(c[2]) + bf2f(d[2])) + c0.z;
        r0.w = (bf2f(a[3]) + bf2f(b[3])) + (bf2f(c[3]) + bf2f(d[3])) + c0.w;
        r1.x = (bf2f(a[4]) + bf2f(b[4])) + (bf2f(c[4]) + bf2f(d[4])) + c1.x;
        r1.y = (bf2f(a[5]) + bf2f(b[5])) + (bf2f(c[5]) + bf2f(d[5])) + c1.y;
        r1.z = (bf2f(a[6]) + bf2f(b[6])) + (bf2f(c[6]) + bf2f(d[6])) + c1.z;
        r1.w = (bf2f(a[7]) + bf2f(b[7])) + (bf2f(c[7]) + bf2f(d[7])) + c1.w;
        *(float4*)(out + e)     = r0;
        *(float4*)(out + e + 4) = r1;
    }
}

// ---- fallback (small ws): KSPLIT=1 structure, grid 256, f32 out + bias ----
__global__ __launch_bounds__(256, 2) void fkan_gemm_fb(const float* __restrict__ x,
                                                       const short* __restrict__ Wb,
                                                       const float* __restrict__ bias,
                                                       float* __restrict__ outp) {
    __shared__ short As[2][128 * 64];
    __shared__ short Bs[2][128 * 64];
    const int bid = blockIdx.x;
    const int xcd = bid & 7, idx = bid >> 3;
    const int bn = xcd & 3, bm = idx + (xcd >> 2) * 32;
    const int n0 = bm * 128, o0 = bn * 128;
    const int tid = threadIdx.x;
    const int wid = tid >> 6, lane = tid & 63;
    const int lrow = lane & 15, lk = lane >> 4;
    const int wr = wid >> 1, wc = wid & 1;
    f32x4 acc[4][4];
#pragma unroll
    for (int a = 0; a < 4; ++a)
#pragma unroll
        for (int b = 0; b < 4; ++b) { f32x4 z = {0,0,0,0}; acc[a][b] = z; }
    const int nl = tid >> 1, isel = tid & 1;
    const float* xrow = x + (n0 + nl) * 512 + isel * 2;
    auto stage = [&](int t, int nb, float2 xvv) {
#pragma unroll
        for (int w = 0; w < 4; ++w) {
            const int chunk = w * 256 + tid;
            const int r = chunk >> 3, pc = chunk & 7;
            const int lc = pc ^ (r & 7);
            const short* src = Wb + (o0 + r) * KDIM + t * 64 + lc * 8;
            short* ldst = &Bs[nb][w * 2048 + wid * 512];
            __builtin_amdgcn_global_load_lds(
                (const __attribute__((address_space(1))) void*)src,
                (__attribute__((address_space(3))) void*)ldst, 16, 0, 0);
        }
#pragma unroll
        for (int ii = 0; ii < 2; ++ii) {
            const float xx = ii ? xvv.y : xvv.x;
            float s1, c1; __sincosf(xx, &s1, &c1);
            float c = c1, s = s1;
            i32x4 lo, hi;
#pragma unroll
            for (int g = 0; g < 8; ++g) {
                const int p = pkbf(c, s);
                if (g < 4) lo[g] = p; else hi[g - 4] = p;
                const float t1 = s * s1, t2 = c * s1;
                const float cn = __builtin_fmaf(c, c1, -t1);
                s = __builtin_fmaf(s, c1, t2); c = cn;
            }
            const int cb0 = (isel * 2 + ii) * 2;
            *(i32x4*)&As[nb][nl * 64 + ((cb0 ^ (nl & 7))) * 8]       = lo;
            *(i32x4*)&As[nb][nl * 64 + (((cb0 + 1) ^ (nl & 7))) * 8] = hi;
        }
    };
    float2 xv = *(const float2*)xrow;
    stage(0, 0, xv);
    xv = *(const float2*)(xrow + 4);
    __syncthreads();
    for (int kt = 0; kt < 128; ++kt) {
        const int cur = kt & 1;
        s16x8 af[2][4], bfr[2][4];
#pragma unroll
        for (int ksub = 0; ksub < 2; ++ksub) {
#pragma unroll
            for (int mf = 0; mf < 4; ++mf) {
                const int row = wr * 64 + mf * 16 + lrow;
                af[ksub][mf] = *(const s16x8*)&As[cur][row * 64 + ((ksub * 4 + lk) ^ (row & 7)) * 8];
            }
#pragma unroll
            for (int nf = 0; nf < 4; ++nf) {
                const int row = wc * 64 + nf * 16 + lrow;
                bfr[ksub][nf] = *(const s16x8*)&Bs[cur][row * 64 + ((ksub * 4 + lk) ^ (row & 7)) * 8];
            }
        }
        if (kt + 1 < 128) {
            stage(kt + 1, cur ^ 1, xv);
            if (kt + 2 < 128) xv = *(const float2*)(xrow + (kt + 2) * 4);
        }
#pragma unroll
        for (int ksub = 0; ksub < 2; ++ksub)
#pragma unroll
            for (int mf = 0; mf < 4; ++mf)
#pragma unroll
                for (int nf = 0; nf < 4; ++nf)
                    acc[mf][nf] = __builtin_amdgcn_mfma_f32_16x16x32_bf16(
                        af[ksub][mf], bfr[ksub][nf], acc[mf][nf], 0, 0, 0);
        __syncthreads();
    }
#pragma unroll
    for (int nf = 0; nf < 4; ++nf) {
        const int oc = o0 + wc * 64 + nf * 16 + lrow;
        const float bv = bias[oc];
#pragma unroll
        for (int mf = 0; mf < 4; ++mf) {
            const f32x4 v = acc[mf][nf];
            const int rbase = n0 + wr * 64 + mf * 16 + lk * 4;
#pragma unroll
            for (int j = 0; j < 4; ++j)
                outp[(size_t)(rbase + j) * 512 + oc] = v[j] + bv;
        }
    }
}

extern "C" void kernel_launch(void* const* d_in, const int* in_sizes, int n_in,
                              void* d_out, int out_size, void* d_ws, size_t ws_size,
                              hipStream_t stream) {
    const float* x    = (const float*)d_in[0];
    const float* cf   = (const float*)d_in[1];
    const float* bias = (const float*)d_in[2];
    float* out = (float*)d_out;

    const size_t partial_bytes = (size_t)4 * NROWS * ODIM * 2;   // 33.6 MB (bf16 x4)
    const size_t wb_bytes = (size_t)ODIM * KDIM * 2;             // 8.4 MB

    if (ws_size >= partial_bytes + wb_bytes) {
        short* P  = (short*)d_ws;
        short* Wb = (short*)((char*)d_ws + partial_bytes);
        fkan_prep<<<512, 256, 0, stream>>>(cf, Wb);
        fkan_gemm17<<<256, 512, 0, stream>>>(x, Wb, P);
        fkan_combine4<<<2048, 256, 0, stream>>>(P, bias, out);
    } else {
        short* Wb = (short*)d_ws;
        fkan_prep<<<512, 256, 0, stream>>>(cf, Wb);
        fkan_gemm_fb<<<256, 256, 0, stream>>>(x, Wb, bias, out);
    }
}